// Round 8
// baseline (5098.068 us; speedup 1.0000x reference)
//
#include <hip/hip_runtime.h>
#include <math.h>

#define B_  32
#define T_  512
#define H_  1024
#define G4_ 4096
#define NT  512

typedef __attribute__((ext_vector_type(8))) _Float16 f16x8;
typedef __attribute__((ext_vector_type(4))) float   f32x4;

__device__ __forceinline__ float hardsig(float z) {
    return fminf(fmaxf(0.2f * z + 0.5f, 0.0f), 1.0f);
}
__device__ __forceinline__ float fast_tanh(float x) {
    float ax = fabsf(x);
    float e  = __expf(-2.0f * ax);
    float t  = (1.0f - e) / (1.0f + e);
    return copysignf(t, x);
}
__device__ __forceinline__ unsigned ldA(const unsigned* p) {
    return __hip_atomic_load(p, __ATOMIC_RELAXED, __HIP_MEMORY_SCOPE_AGENT);
}
__device__ __forceinline__ void stA32(unsigned* p, unsigned v) {
    __hip_atomic_store(p, v, __ATOMIC_RELAXED, __HIP_MEMORY_SCOPE_AGENT);
}

// ctr layout (dwords, 64B-spaced):
//  d0 leaves @ [leaf*16] (8)   | d0 root @ [128] | gen0 reps @ [144+i*16] (16)
//  d1 leaves @ [400+leaf*16]   | d1 root @ [656] | gen1 reps @ [672+i*16]
//  eng cnt  @ [928]            | xzgen reps @ [944+i*16]

__global__ __launch_bounds__(NT, 1)
void lstm8(const float* __restrict__ x,
           const float* __restrict__ W0, const float* __restrict__ U0, const float* __restrict__ b0,
           const float* __restrict__ W1, const float* __restrict__ U1, const float* __restrict__ b1,
           _Float16* __restrict__ h1,       // [T][B][H] fp16 (fresh addresses)
           _Float16* __restrict__ h2,       // [T][B][H] fp16 (fresh addresses)
           _Float16* __restrict__ xzr,      // [4][8][B][4H] fp16 ring
           const _Float16* __restrict__ zp, // [B][H] fp16 zeros
           unsigned* __restrict__ ctr,
           float* __restrict__ out)         // [B][H] fp32
{
    __shared__ __align__(16) char smem[139776];
    _Float16* Wl  = (_Float16*)smem;            // 128 KiB fragment-ordered weights
    float*    red = (float*)(smem + 131072);    // 8.5 KiB partial C tiles

    const int tid = threadIdx.x, bid = blockIdx.x;
    const int w = tid >> 6, l = tid & 63;
    const int koff = (l >> 4) * 8;

    // ============================ xz ENGINE (bid 192..255) ============================
    if (bid >= 192) {
        const int e = bid - 192, gbase = e * 64;   // owns gate-cols [e*64, e*64+64)
        for (int fi = tid; fi < 16384; fi += NT) { // convert W0 slice -> frag LDS
            const int k = fi >> 4, rem = fi & 15;
            const float* src = W0 + (size_t)k * G4_ + gbase + rem * 4;
            float4 v = *(const float4*)src;
            const int kiG = k >> 5, jsub = 16 * ((k & 31) >> 3), e8 = k & 7;
            #pragma unroll
            for (int c = 0; c < 4; ++c) {
                const int j = rem * 4 + c, nf = j >> 4, lane = (j & 15) + jsub;
                float fv = (c == 0) ? v.x : (c == 1) ? v.y : (c == 2) ? v.z : v.w;
                Wl[((nf * 32 + kiG) * 64 + lane) * 8 + e8] = (_Float16)fv;
            }
        }
        __syncthreads();

        for (int c = 0; c < 64; ++c) {
            if (c >= 4 && tid == 0) {   // ring-slot reuse guard (dom0 consumed slot)
                const unsigned need = (unsigned)(8 * c - 24);
                while (ldA(&ctr[144 + (e & 15) * 16]) < need) __builtin_amdgcn_s_sleep(1);
            }
            __syncthreads();

            f32x4 acc[2][4];
            #pragma unroll
            for (int p = 0; p < 2; ++p)
                #pragma unroll
                for (int nf = 0; nf < 4; ++nf) acc[p][nf] = (f32x4){0.f, 0.f, 0.f, 0.f};
            const float* xrow[2];
            #pragma unroll
            for (int p = 0; p < 2; ++p) {
                const int m = (w * 2 + p) * 16 + (l & 15);
                xrow[p] = x + ((size_t)(m & 31) * T_ + (8 * c + (m >> 5))) * 1024;
            }
            #pragma unroll 4
            for (int kiG = 0; kiG < 32; ++kiG) {
                const int kk = kiG * 32 + koff;
                f16x8 af[2];
                #pragma unroll
                for (int p = 0; p < 2; ++p) {
                    float4 v0 = *(const float4*)&xrow[p][kk];
                    float4 v1 = *(const float4*)&xrow[p][kk + 4];
                    af[p][0]=(_Float16)v0.x; af[p][1]=(_Float16)v0.y;
                    af[p][2]=(_Float16)v0.z; af[p][3]=(_Float16)v0.w;
                    af[p][4]=(_Float16)v1.x; af[p][5]=(_Float16)v1.y;
                    af[p][6]=(_Float16)v1.z; af[p][7]=(_Float16)v1.w;
                }
                #pragma unroll
                for (int nf = 0; nf < 4; ++nf) {
                    f16x8 bf = *(const f16x8*)&Wl[((nf * 32 + kiG) * 64 + l) * 8];
                    acc[0][nf] = __builtin_amdgcn_mfma_f32_16x16x32_f16(af[0], bf, acc[0][nf], 0, 0, 0);
                    acc[1][nf] = __builtin_amdgcn_mfma_f32_16x16x32_f16(af[1], bf, acc[1][nf], 0, 0, 0);
                }
            }
            #pragma unroll
            for (int p = 0; p < 2; ++p)
                #pragma unroll
                for (int nf = 0; nf < 4; ++nf)
                    #pragma unroll
                    for (int i = 0; i < 4; ++i) {
                        _Float16 hf = (_Float16)acc[p][nf][i];
                        unsigned short us; __builtin_memcpy(&us, &hf, 2);
                        unsigned up = us;
                        unsigned op = (unsigned)__shfl_xor((int)up, 1);
                        if (!(l & 1)) {
                            const int m = (w * 2 + p) * 16 + (l >> 4) * 4 + i;
                            size_t off = (((size_t)(c & 3) * 8 + (m >> 5)) * B_ + (m & 31)) * G4_
                                       + gbase + nf * 16 + ((l & 15) & ~1);
                            stA32((unsigned*)&xzr[off], up | (op << 16));
                        }
                    }
            asm volatile("s_waitcnt vmcnt(0)" ::: "memory");
            __syncthreads();
            if (tid == 0) {
                unsigned old = __hip_atomic_fetch_add(&ctr[928], 1u, __ATOMIC_RELAXED, __HIP_MEMORY_SCOPE_AGENT);
                if ((old & 63u) == 63u) {
                    #pragma unroll
                    for (int i = 0; i < 16; ++i) stA32(&ctr[944 + i * 16], (unsigned)(c + 1));
                }
            }
        }
        return;
    }

    // ============================ RECURRENCE DOMAINS ============================
    const int dom = (bid >= 64);

    if (dom == 0) {
        // -------- layer-0: 64 blocks x 16 h-cols --------
        const int jb = bid * 16;
        for (int fi = tid; fi < 16384; fi += NT) {   // convert U0 -> frag LDS
            const int k = fi >> 4, rem = fi & 15, g = rem >> 2, jq = (rem & 3) * 4;
            const float* src = U0 + (size_t)k * G4_ + g * 1024 + jb + jq;
            float4 v = *(const float4*)src;
            const int kiG = k >> 5, jsub = 16 * ((k & 31) >> 3), e8 = k & 7;
            #pragma unroll
            for (int c = 0; c < 4; ++c) {
                const int lane = (jq + c) + jsub;
                float fv = (c == 0) ? v.x : (c == 1) ? v.y : (c == 2) ? v.z : v.w;
                Wl[((g * 32 + kiG) * 64 + lane) * 8 + e8] = (_Float16)fv;
            }
        }
        const int bb = tid >> 4, jj = tid & 15, jcol = jb + jj;
        float bias4[4];
        #pragma unroll
        for (int g = 0; g < 4; ++g) bias4[g] = b0[(size_t)g * H_ + jcol];
        float creg = 0.f;
        const int mt = w >> 2, g = w & 3;
        const int arow = mt * 16 + (l & 15);
        __syncthreads();

        for (int t = 0; t < T_; ++t) {
            // parallel poll: lane0 -> xzgen, lane1 -> gen0
            if (tid < 2) {
                const unsigned* p = tid ? &ctr[144 + (bid & 15) * 16] : &ctr[944 + (bid & 15) * 16];
                const unsigned tgt = tid ? (unsigned)t : (unsigned)((t >> 3) + 1);
                bool ok = (tid == 1 && t == 0);
                while (true) {
                    ok = ok || (ldA(p) >= tgt);
                    if (__all((int)ok)) break;
                    __builtin_amdgcn_s_sleep(1);
                }
            }
            asm volatile("" ::: "memory");
            __syncthreads();   // S1

            // xz slice loads (ring recycles addresses -> bypass L2), consumed in combine
            unsigned xzd[4];
            {
                const size_t xbase = (((size_t)((t >> 3) & 3) * 8 + (t & 7)) * B_ + bb) * G4_;
                #pragma unroll
                for (int gg = 0; gg < 4; ++gg)
                    xzd[gg] = ldA((const unsigned*)&xzr[xbase + gg * 1024 + jb + (jj & ~1)]);
            }

            // MFMA: A = h1[t-1] direct cached loads (fresh addresses), B = LDS frags
            const _Float16* hp = t ? h1 + ((size_t)(t - 1) * B_ + arow) * H_
                                   : zp + (size_t)arow * H_;
            f32x4 acc = {0.f, 0.f, 0.f, 0.f};
            #pragma unroll 8
            for (int kiG = 0; kiG < 32; ++kiG) {
                f16x8 af = *(const f16x8*)&hp[kiG * 32 + koff];
                f16x8 bf = *(const f16x8*)&Wl[((g * 32 + kiG) * 64 + l) * 8];
                acc = __builtin_amdgcn_mfma_f32_16x16x32_f16(af, bf, acc, 0, 0, 0);
            }
            #pragma unroll
            for (int i = 0; i < 4; ++i)
                red[((mt * 4 + g) * 16 + (l >> 4) * 4 + i) * 17 + (l & 15)] = acc[i];
            __syncthreads();   // S2

            // combine (no cross-wave sum: wave (mt,g) produced full z[g] tile)
            {
                float z[4];
                #pragma unroll
                for (int gg = 0; gg < 4; ++gg) {
                    float xv;
                    {
                        unsigned dv = xzd[gg];
                        unsigned short hb = (jj & 1) ? (unsigned short)(dv >> 16) : (unsigned short)(dv & 0xffffu);
                        _Float16 hf; __builtin_memcpy(&hf, &hb, 2);
                        xv = (float)hf;
                    }
                    z[gg] = red[(((bb >> 4) * 4 + gg) * 16 + (bb & 15)) * 17 + jj] + xv + bias4[gg];
                }
                float ig = hardsig(z[0]), fg = hardsig(z[1]);
                float gg2 = fast_tanh(z[2]), og = hardsig(z[3]);
                creg = fg * creg + ig * gg2;
                float hval = og * fast_tanh(creg);
                _Float16 hf = (_Float16)hval;
                unsigned short us; __builtin_memcpy(&us, &hf, 2);
                unsigned up = us;
                unsigned op = (unsigned)__shfl_xor((int)up, 1);
                if (!(tid & 1))
                    stA32((unsigned*)&h1[((size_t)t * B_ + bb) * H_ + (jcol & ~1)], up | (op << 16));
            }
            asm volatile("s_waitcnt vmcnt(0)" ::: "memory");
            __syncthreads();   // S3: all waves' publishes ACKed

            if (tid == 0) {
                unsigned old = __hip_atomic_fetch_add(&ctr[(bid >> 3) * 16], 1u, __ATOMIC_RELAXED, __HIP_MEMORY_SCOPE_AGENT);
                if ((old & 7u) == 7u) {
                    unsigned r = __hip_atomic_fetch_add(&ctr[128], 1u, __ATOMIC_RELAXED, __HIP_MEMORY_SCOPE_AGENT);
                    if ((r & 7u) == 7u) {
                        #pragma unroll
                        for (int i = 0; i < 16; ++i) stA32(&ctr[144 + i * 16], (unsigned)(t + 1));
                    }
                }
            }
        }
    } else {
        // -------- layer-1: 128 blocks x 8 h-cols --------
        const int db = bid - 64, jb8 = db * 8;
        for (int m = 0; m < 2; ++m) {                 // convert W1,U1 -> frag LDS
            const float* M = m ? U1 : W1;
            for (int fi = tid; fi < 8192; fi += NT) {
                const int k = fi >> 3, rem = fi & 7, g = rem >> 1, jq = (rem & 1) * 4;
                const float* src = M + (size_t)k * G4_ + g * 1024 + jb8 + jq;
                float4 v = *(const float4*)src;
                const int kiG = k >> 5, jsub = 16 * ((k & 31) >> 3), e8 = k & 7;
                #pragma unroll
                for (int c = 0; c < 4; ++c) {
                    const int j = g * 8 + jq + c, nf = j >> 4, lane = (j & 15) + jsub;
                    float fv = (c == 0) ? v.x : (c == 1) ? v.y : (c == 2) ? v.z : v.w;
                    Wl[(((m * 2 + nf) * 32 + kiG) * 64 + lane) * 8 + e8] = (_Float16)fv;
                }
            }
        }
        const int bb = tid >> 3, jj = tid & 7, jcol = jb8 + jj;   // combine map (tid<256)
        float bias4[4];
        if (tid < 256) {
            #pragma unroll
            for (int g = 0; g < 4; ++g) bias4[g] = b1[(size_t)g * H_ + jcol];
        }
        float creg = 0.f;
        const int role = w >> 2, mt = (w >> 1) & 1, nf = w & 1;
        const int arow = mt * 16 + (l & 15);
        __syncthreads();

        for (int t = 0; t < T_; ++t) {
            // parallel poll: lane0 -> gen0 (h1[t] ready), lane1 -> gen1 (h2[t-1] ready)
            if (tid < 2) {
                const unsigned* p = tid ? &ctr[672 + (db & 15) * 16] : &ctr[144 + (db & 15) * 16];
                const unsigned tgt = tid ? (unsigned)t : (unsigned)(t + 1);
                bool ok = (tid == 1 && t == 0);
                while (true) {
                    ok = ok || (ldA(p) >= tgt);
                    if (__all((int)ok)) break;
                    __builtin_amdgcn_s_sleep(1);
                }
            }
            asm volatile("" ::: "memory");
            __syncthreads();   // S1

            const _Float16* hp;
            if (role == 0) hp = h1 + ((size_t)t * B_ + arow) * H_;
            else           hp = t ? h2 + ((size_t)(t - 1) * B_ + arow) * H_
                                  : zp + (size_t)arow * H_;
            f32x4 acc = {0.f, 0.f, 0.f, 0.f};
            #pragma unroll 8
            for (int kiG = 0; kiG < 32; ++kiG) {
                f16x8 af = *(const f16x8*)&hp[kiG * 32 + koff];
                f16x8 bf = *(const f16x8*)&Wl[(((role * 2 + nf) * 32 + kiG) * 64 + l) * 8];
                acc = __builtin_amdgcn_mfma_f32_16x16x32_f16(af, bf, acc, 0, 0, 0);
            }
            #pragma unroll
            for (int i = 0; i < 4; ++i)
                red[((role * 4 + mt * 2 + nf) * 16 + (l >> 4) * 4 + i) * 17 + (l & 15)] = acc[i];
            __syncthreads();   // S2

            if (tid < 256) {
                const int rmt = bb >> 4, row = bb & 15;
                float z[4];
                #pragma unroll
                for (int g = 0; g < 4; ++g) {
                    const int j = g * 8 + jj, nff = j >> 4, col = j & 15;
                    z[g] = red[((0 * 4 + rmt * 2 + nff) * 16 + row) * 17 + col]
                         + red[((1 * 4 + rmt * 2 + nff) * 16 + row) * 17 + col] + bias4[g];
                }
                float ig = hardsig(z[0]), fg = hardsig(z[1]);
                float gg2 = fast_tanh(z[2]), og = hardsig(z[3]);
                creg = fg * creg + ig * gg2;
                float hval = og * fast_tanh(creg);
                _Float16 hf = (_Float16)hval;
                unsigned short us; __builtin_memcpy(&us, &hf, 2);
                unsigned up = us;
                unsigned op = (unsigned)__shfl_xor((int)up, 1);
                if (!(tid & 1))
                    stA32((unsigned*)&h2[((size_t)t * B_ + bb) * H_ + (jcol & ~1)], up | (op << 16));
                if (t == T_ - 1) out[(size_t)bb * H_ + jcol] = hval;
            }
            asm volatile("s_waitcnt vmcnt(0)" ::: "memory");
            __syncthreads();   // S3

            if (tid == 0) {
                unsigned old = __hip_atomic_fetch_add(&ctr[400 + (db >> 3) * 16], 1u, __ATOMIC_RELAXED, __HIP_MEMORY_SCOPE_AGENT);
                if ((old & 7u) == 7u) {
                    unsigned r = __hip_atomic_fetch_add(&ctr[656], 1u, __ATOMIC_RELAXED, __HIP_MEMORY_SCOPE_AGENT);
                    if ((r & 15u) == 15u) {
                        #pragma unroll
                        for (int i = 0; i < 16; ++i) stA32(&ctr[672 + i * 16], (unsigned)(t + 1));
                    }
                }
            }
        }
    }
}

extern "C" void kernel_launch(void* const* d_in, const int* in_sizes, int n_in,
                              void* d_out, int out_size, void* d_ws, size_t ws_size,
                              hipStream_t stream) {
    const float* x  = (const float*)d_in[0];
    const float* W0 = (const float*)d_in[1];
    const float* U0 = (const float*)d_in[2];
    const float* b0 = (const float*)d_in[3];
    const float* W1 = (const float*)d_in[4];
    const float* U1 = (const float*)d_in[5];
    const float* b1 = (const float*)d_in[6];
    float* out = (float*)d_out;

    char* ws = (char*)d_ws;
    const size_t off_h1 = 0;          // 32 MiB  h1 fp16 [T][B][H]
    const size_t off_h2 = 33554432;   // 32 MiB  h2 fp16 [T][B][H]
    const size_t off_xz = 67108864;   //  8 MiB  xz ring fp16 [4][8][B][4H]
    const size_t off_zp = 75497472;   // 64 KiB  fp16 zeros
    const size_t off_ct = 75563008;   //  8 KiB  counters

    _Float16* h1  = (_Float16*)(ws + off_h1);
    _Float16* h2  = (_Float16*)(ws + off_h2);
    _Float16* xzr = (_Float16*)(ws + off_xz);
    _Float16* zp  = (_Float16*)(ws + off_zp);
    unsigned* ctr = (unsigned*)(ws + off_ct);

    // reset zero page + counters every launch (graph-capture safe)
    hipMemsetAsync(ws + off_zp, 0, 65536 + 8192, stream);

    hipLaunchKernelGGL(lstm8, dim3(256), dim3(NT), 0, stream,
                       x, W0, U0, b0, W1, U1, b1,
                       h1, h2, xzr, zp, ctr, out);
}

// Round 9
// 5019.074 us; speedup vs baseline: 1.0157x; 1.0157x over previous
//
#include <hip/hip_runtime.h>
#include <math.h>

#define B_  32
#define T_  512
#define H_  1024
#define G4_ 4096
#define NT  512

typedef __attribute__((ext_vector_type(8))) _Float16 f16x8;
typedef __attribute__((ext_vector_type(4))) float   f32x4;

__device__ __forceinline__ float hardsig(float z) {
    return fminf(fmaxf(0.2f * z + 0.5f, 0.0f), 1.0f);
}
__device__ __forceinline__ float fast_tanh(float x) {
    float ax = fabsf(x);
    float e  = __expf(-2.0f * ax);
    float t  = (1.0f - e) / (1.0f + e);
    return copysignf(t, x);
}
__device__ __forceinline__ unsigned ldA(const unsigned* p) {
    return __hip_atomic_load(p, __ATOMIC_RELAXED, __HIP_MEMORY_SCOPE_AGENT);
}
__device__ __forceinline__ void stA32(unsigned* p, unsigned v) {
    __hip_atomic_store(p, v, __ATOMIC_RELAXED, __HIP_MEMORY_SCOPE_AGENT);
}
__device__ __forceinline__ unsigned long long ldA64(const void* p) {
    return __hip_atomic_load((const unsigned long long*)p, __ATOMIC_RELAXED, __HIP_MEMORY_SCOPE_AGENT);
}
__device__ __forceinline__ void stA64(void* p, unsigned long long v) {
    __hip_atomic_store((unsigned long long*)p, v, __ATOMIC_RELAXED, __HIP_MEMORY_SCOPE_AGENT);
}
__device__ __forceinline__ float f16bits_to_f(unsigned short us) {
    _Float16 hf; __builtin_memcpy(&hf, &us, 2);
    return (float)hf;
}

// ctr layout (dwords, 64B-spaced groups):
//  gen0 reps @ [i*16] (16) | gen1 reps @ [256+i*16] | xzgen reps @ [512+i*16]
//  d0 leaves @ [768+i*16] (16) | d0 root @ [1024]
//  d1 leaves @ [1088+i*16] (16) | d1 root @ [1344] | eng cnt @ [1360]

__global__ __launch_bounds__(NT, 1)
void lstm9(const float* __restrict__ x,
           const float* __restrict__ W0, const float* __restrict__ U0, const float* __restrict__ b0,
           const float* __restrict__ W1, const float* __restrict__ U1, const float* __restrict__ b1,
           _Float16* __restrict__ h1,       // [T][B][H] fp16
           _Float16* __restrict__ h2,       // [T][B][H] fp16
           _Float16* __restrict__ xzr,      // [4][8][B][4H] fp16 ring (bias-folded)
           const _Float16* __restrict__ zp, // [B][H] fp16 zeros
           unsigned* __restrict__ ctr,
           float* __restrict__ out)         // [B][H] fp32
{
    __shared__ __align__(16) char smem[148992];
    _Float16* Wl  = (_Float16*)smem;            // 128 KiB fragment-ordered weights
    float*    red = (float*)(smem + 131072);    // 17408 B [par][slot8][16][17]
    #define RED(par, slot, row, col) red[(((par) * 8 + (slot)) * 16 + (row)) * 17 + (col)]

    const int tid = threadIdx.x, bid = blockIdx.x;
    const int w = tid >> 6, l = tid & 63;
    const int koff = (l >> 4) * 8;

    // ============================ xz ENGINE (bid 192..255) ============================
    if (bid >= 192) {
        const int e = bid - 192, gbase = e * 64;
        for (int fi = tid; fi < 16384; fi += NT) {
            const int k = fi >> 4, rem = fi & 15;
            const float* src = W0 + (size_t)k * G4_ + gbase + rem * 4;
            float4 v = *(const float4*)src;
            const int kiG = k >> 5, jsub = 16 * ((k & 31) >> 3), e8 = k & 7;
            #pragma unroll
            for (int c = 0; c < 4; ++c) {
                const int j = rem * 4 + c, nf = j >> 4, lane = (j & 15) + jsub;
                float fv = (c == 0) ? v.x : (c == 1) ? v.y : (c == 2) ? v.z : v.w;
                Wl[((nf * 32 + kiG) * 64 + lane) * 8 + e8] = (_Float16)fv;
            }
        }
        float bb0[4];
        #pragma unroll
        for (int nf = 0; nf < 4; ++nf) bb0[nf] = b0[gbase + nf * 16 + (l & 15)];
        __syncthreads();

        for (int c = 0; c < 64; ++c) {
            if (c >= 4 && tid == 0) {   // slot reuse: dom0 must have consumed chunk c-4
                const unsigned need = (unsigned)(8 * c - 24);
                while (ldA(&ctr[(e & 15) * 16]) < need) __builtin_amdgcn_s_sleep(1);
            }
            __syncthreads();

            f32x4 acc[2][4];
            #pragma unroll
            for (int p = 0; p < 2; ++p)
                #pragma unroll
                for (int nf = 0; nf < 4; ++nf) acc[p][nf] = (f32x4){0.f, 0.f, 0.f, 0.f};
            const float* xrow[2];
            #pragma unroll
            for (int p = 0; p < 2; ++p) {
                const int m = (w * 2 + p) * 16 + (l & 15);
                xrow[p] = x + ((size_t)(m & 31) * T_ + (8 * c + (m >> 5))) * 1024;
            }
            #pragma unroll 4
            for (int kiG = 0; kiG < 32; ++kiG) {
                const int kk = kiG * 32 + koff;
                f16x8 af[2];
                #pragma unroll
                for (int p = 0; p < 2; ++p) {
                    float4 v0 = *(const float4*)&xrow[p][kk];
                    float4 v1 = *(const float4*)&xrow[p][kk + 4];
                    af[p][0]=(_Float16)v0.x; af[p][1]=(_Float16)v0.y;
                    af[p][2]=(_Float16)v0.z; af[p][3]=(_Float16)v0.w;
                    af[p][4]=(_Float16)v1.x; af[p][5]=(_Float16)v1.y;
                    af[p][6]=(_Float16)v1.z; af[p][7]=(_Float16)v1.w;
                }
                #pragma unroll
                for (int nf = 0; nf < 4; ++nf) {
                    f16x8 bf = *(const f16x8*)&Wl[((nf * 32 + kiG) * 64 + l) * 8];
                    acc[0][nf] = __builtin_amdgcn_mfma_f32_16x16x32_f16(af[0], bf, acc[0][nf], 0, 0, 0);
                    acc[1][nf] = __builtin_amdgcn_mfma_f32_16x16x32_f16(af[1], bf, acc[1][nf], 0, 0, 0);
                }
            }
            #pragma unroll
            for (int p = 0; p < 2; ++p)
                #pragma unroll
                for (int nf = 0; nf < 4; ++nf)
                    #pragma unroll
                    for (int i = 0; i < 4; ++i) {
                        _Float16 hf = (_Float16)(acc[p][nf][i] + bb0[nf]);   // bias folded
                        unsigned short us; __builtin_memcpy(&us, &hf, 2);
                        unsigned up = us;
                        unsigned op = (unsigned)__shfl_xor((int)up, 1);
                        if (!(l & 1)) {
                            const int m = (w * 2 + p) * 16 + (l >> 4) * 4 + i;
                            size_t off = (((size_t)(c & 3) * 8 + (m >> 5)) * B_ + (m & 31)) * G4_
                                       + gbase + nf * 16 + ((l & 15) & ~1);
                            stA32((unsigned*)&xzr[off], up | (op << 16));
                        }
                    }
            asm volatile("s_waitcnt vmcnt(0)" ::: "memory");
            __syncthreads();
            if (tid == 0) {
                unsigned old = __hip_atomic_fetch_add(&ctr[1360], 1u, __ATOMIC_RELAXED, __HIP_MEMORY_SCOPE_AGENT);
                if ((old & 63u) == 63u) {
                    #pragma unroll
                    for (int i = 0; i < 16; ++i) stA32(&ctr[512 + i * 16], (unsigned)(c + 1));
                }
            }
        }
        return;
    }

    // ============================ DOM0: layer-0, 64 blocks x 16 cols ============================
    if (bid < 64) {
        const int jb = bid * 16;
        for (int fi = tid; fi < 16384; fi += NT) {   // U0 -> frag LDS
            const int k = fi >> 4, rem = fi & 15, g = rem >> 2, jq = (rem & 3) * 4;
            const float* src = U0 + (size_t)k * G4_ + g * 1024 + jb + jq;
            float4 v = *(const float4*)src;
            const int kiG = k >> 5, jsub = 16 * ((k & 31) >> 3), e8 = k & 7;
            #pragma unroll
            for (int c = 0; c < 4; ++c) {
                const int lane = (jq + c) + jsub;
                float fv = (c == 0) ? v.x : (c == 1) ? v.y : (c == 2) ? v.z : v.w;
                Wl[((g * 32 + kiG) * 64 + lane) * 8 + e8] = (_Float16)fv;
            }
        }
        const int mt = w >> 2, g = w & 3;
        const int arow = mt * 16 + (l & 15);
        const int cidx = w * 64 + l;             // combine thread id (valid w<2)
        const int cb = cidx >> 2, j4 = (cidx & 3) * 4;
        float creg[4] = {0.f, 0.f, 0.f, 0.f};
        const unsigned* g0rep = &ctr[(bid & 15) * 16];
        const unsigned* xzrep = &ctr[512 + (bid & 15) * 16];
        __syncthreads();

        for (int t = 0; t < T_; ++t) {
            const int par = t & 1;
            // per-wave poll
            if (w < 2) {
                if (l < 2) {
                    const unsigned* p = l ? xzrep : g0rep;
                    const unsigned tgt = l ? (unsigned)((t >> 3) + 1) : (unsigned)t;
                    bool ok = (!l && t == 0);
                    while (true) {
                        ok = ok || (ldA(p) >= tgt);
                        if (__all((int)ok)) break;
                        __builtin_amdgcn_s_sleep(1);
                    }
                }
            } else if (t > 0) {
                if (l == 0)
                    while (ldA(g0rep) < (unsigned)t) __builtin_amdgcn_s_sleep(1);
            }
            asm volatile("" ::: "memory");

            // combine waves: issue xz loads early (overlap with MFMA)
            unsigned long long xzq[4];
            if (w < 2) {
                const size_t xbase = (((size_t)((t >> 3) & 3) * 8 + (t & 7)) * B_ + cb) * G4_ + jb + j4;
                #pragma unroll
                for (int gg = 0; gg < 4; ++gg) xzq[gg] = ldA64(&xzr[xbase + gg * 1024]);
            }

            // A-loads fully hoisted, 4 MFMA chains
            const _Float16* hp = t ? h1 + ((size_t)(t - 1) * B_ + arow) * H_
                                   : zp + (size_t)arow * H_;
            f16x8 a[32];
            #pragma unroll
            for (int k = 0; k < 32; ++k) a[k] = *(const f16x8*)&hp[k * 32 + koff];
            f32x4 ac0 = {0,0,0,0}, ac1 = {0,0,0,0}, ac2 = {0,0,0,0}, ac3 = {0,0,0,0};
            #pragma unroll
            for (int k = 0; k < 32; k += 4) {
                ac0 = __builtin_amdgcn_mfma_f32_16x16x32_f16(a[k+0], *(const f16x8*)&Wl[((g*32+k+0)*64+l)*8], ac0, 0, 0, 0);
                ac1 = __builtin_amdgcn_mfma_f32_16x16x32_f16(a[k+1], *(const f16x8*)&Wl[((g*32+k+1)*64+l)*8], ac1, 0, 0, 0);
                ac2 = __builtin_amdgcn_mfma_f32_16x16x32_f16(a[k+2], *(const f16x8*)&Wl[((g*32+k+2)*64+l)*8], ac2, 0, 0, 0);
                ac3 = __builtin_amdgcn_mfma_f32_16x16x32_f16(a[k+3], *(const f16x8*)&Wl[((g*32+k+3)*64+l)*8], ac3, 0, 0, 0);
            }
            f32x4 acc = (ac0 + ac1) + (ac2 + ac3);
            #pragma unroll
            for (int i = 0; i < 4; ++i)
                RED(par, mt * 4 + g, (l >> 4) * 4 + i, (l & 15)) = acc[i];
            __syncthreads();   // the only per-step barrier

            if (w < 2) {
                asm volatile("s_waitcnt vmcnt(0)" ::: "memory");   // xz loads done
                const int rmt = cb >> 4, row = cb & 15;
                unsigned long long pk = 0;
                float hv4[4];
                #pragma unroll
                for (int c = 0; c < 4; ++c) {
                    float z[4];
                    #pragma unroll
                    for (int gg = 0; gg < 4; ++gg) {
                        float xv = f16bits_to_f((unsigned short)((xzq[gg] >> (16 * c)) & 0xffffu));
                        z[gg] = RED(par, rmt * 4 + gg, row, j4 + c) + xv;
                    }
                    float ig = hardsig(z[0]), fg = hardsig(z[1]);
                    float gv = fast_tanh(z[2]), og = hardsig(z[3]);
                    creg[c] = fg * creg[c] + ig * gv;
                    hv4[c] = og * fast_tanh(creg[c]);
                    _Float16 hf = (_Float16)hv4[c];
                    unsigned short us; __builtin_memcpy(&us, &hf, 2);
                    pk |= ((unsigned long long)us) << (16 * c);
                }
                stA64(&h1[((size_t)t * B_ + cb) * H_ + jb + j4], pk);
                asm volatile("s_waitcnt vmcnt(0)" ::: "memory");
                if (l == 0) {
                    unsigned old = __hip_atomic_fetch_add(&ctr[768 + (bid >> 2) * 16], 1u, __ATOMIC_RELAXED, __HIP_MEMORY_SCOPE_AGENT);
                    if ((old & 7u) == 7u) {
                        unsigned r = __hip_atomic_fetch_add(&ctr[1024], 1u, __ATOMIC_RELAXED, __HIP_MEMORY_SCOPE_AGENT);
                        if ((r & 15u) == 15u) {
                            #pragma unroll
                            for (int i = 0; i < 16; ++i) stA32(&ctr[i * 16], (unsigned)(t + 1));
                        }
                    }
                }
            }
        }
        return;
    }

    // ============================ DOM1: layer-1, 128 blocks x 8 cols ============================
    {
        const int db = bid - 64, jb8 = db * 8;
        for (int m = 0; m < 2; ++m) {                 // W1,U1 -> frag LDS
            const float* M = m ? U1 : W1;
            for (int fi = tid; fi < 8192; fi += NT) {
                const int k = fi >> 3, rem = fi & 7, g = rem >> 1, jq = (rem & 1) * 4;
                const float* src = M + (size_t)k * G4_ + g * 1024 + jb8 + jq;
                float4 v = *(const float4*)src;
                const int kiG = k >> 5, jsub = 16 * ((k & 31) >> 3), e8 = k & 7;
                #pragma unroll
                for (int c = 0; c < 4; ++c) {
                    const int j = g * 8 + jq + c, nf = j >> 4, lane = (j & 15) + jsub;
                    float fv = (c == 0) ? v.x : (c == 1) ? v.y : (c == 2) ? v.z : v.w;
                    Wl[(((m * 2 + nf) * 32 + kiG) * 64 + lane) * 8 + e8] = (_Float16)fv;
                }
            }
        }
        const int role = w >> 2, mt = (w >> 1) & 1, nf = w & 1;
        const int arow = mt * 16 + (l & 15);
        const int cidx = w * 64 + l;             // combine thread id (valid w<2)
        const int cb = cidx >> 2, j2 = (cidx & 3) * 2;
        float creg[2] = {0.f, 0.f};
        float bias_[4][2];
        if (w < 2) {
            #pragma unroll
            for (int g = 0; g < 4; ++g)
                #pragma unroll
                for (int c = 0; c < 2; ++c)
                    bias_[g][c] = b1[(size_t)g * H_ + jb8 + j2 + c];
        }
        const unsigned* g0rep = &ctr[(db & 15) * 16];
        const unsigned* g1rep = &ctr[256 + (db & 15) * 16];
        __syncthreads();

        for (int t = 0; t < T_; ++t) {
            const int par = t & 1;
            // per-role polls (role0 needs gen0>=t+1 and red-parity guard gen1>=t-1)
            if (role == 0) {
                if (l < 2) {
                    const unsigned* p = l ? g1rep : g0rep;
                    const unsigned tgt = l ? (unsigned)(t - 1) : (unsigned)(t + 1);
                    bool ok = (l && t < 2);
                    while (true) {
                        ok = ok || (ldA(p) >= tgt);
                        if (__all((int)ok)) break;
                        __builtin_amdgcn_s_sleep(1);
                    }
                }
            } else if (t > 0) {
                if (l == 0)
                    while (ldA(g1rep) < (unsigned)t) __builtin_amdgcn_s_sleep(1);
            }
            asm volatile("" ::: "memory");

            const _Float16* hp;
            if (role == 0) hp = h1 + ((size_t)t * B_ + arow) * H_;
            else           hp = t ? h2 + ((size_t)(t - 1) * B_ + arow) * H_
                                  : zp + (size_t)arow * H_;
            f16x8 a[32];
            #pragma unroll
            for (int k = 0; k < 32; ++k) a[k] = *(const f16x8*)&hp[k * 32 + koff];
            const int ws8 = (role * 2 + nf) * 32;
            f32x4 ac0 = {0,0,0,0}, ac1 = {0,0,0,0}, ac2 = {0,0,0,0}, ac3 = {0,0,0,0};
            #pragma unroll
            for (int k = 0; k < 32; k += 4) {
                ac0 = __builtin_amdgcn_mfma_f32_16x16x32_f16(a[k+0], *(const f16x8*)&Wl[((ws8+k+0)*64+l)*8], ac0, 0, 0, 0);
                ac1 = __builtin_amdgcn_mfma_f32_16x16x32_f16(a[k+1], *(const f16x8*)&Wl[((ws8+k+1)*64+l)*8], ac1, 0, 0, 0);
                ac2 = __builtin_amdgcn_mfma_f32_16x16x32_f16(a[k+2], *(const f16x8*)&Wl[((ws8+k+2)*64+l)*8], ac2, 0, 0, 0);
                ac3 = __builtin_amdgcn_mfma_f32_16x16x32_f16(a[k+3], *(const f16x8*)&Wl[((ws8+k+3)*64+l)*8], ac3, 0, 0, 0);
            }
            f32x4 acc = (ac0 + ac1) + (ac2 + ac3);
            #pragma unroll
            for (int i = 0; i < 4; ++i)
                RED(par, role * 4 + mt * 2 + nf, (l >> 4) * 4 + i, (l & 15)) = acc[i];
            __syncthreads();   // the only per-step barrier

            if (w < 2) {
                const int rmt = cb >> 4, row = cb & 15;
                unsigned pk = 0;
                float hv2[2];
                #pragma unroll
                for (int c = 0; c < 2; ++c) {
                    float z[4];
                    #pragma unroll
                    for (int g = 0; g < 4; ++g) {
                        const int j = g * 8 + j2 + c, nff = j >> 4, fc = j & 15;
                        z[g] = RED(par, 0 + rmt * 2 + nff, row, fc)
                             + RED(par, 4 + rmt * 2 + nff, row, fc) + bias_[g][c];
                    }
                    float ig = hardsig(z[0]), fg = hardsig(z[1]);
                    float gv = fast_tanh(z[2]), og = hardsig(z[3]);
                    creg[c] = fg * creg[c] + ig * gv;
                    hv2[c] = og * fast_tanh(creg[c]);
                    _Float16 hf = (_Float16)hv2[c];
                    unsigned short us; __builtin_memcpy(&us, &hf, 2);
                    pk |= ((unsigned)us) << (16 * c);
                }
                stA32((unsigned*)&h2[((size_t)t * B_ + cb) * H_ + jb8 + j2], pk);
                if (t == T_ - 1) *(float2*)&out[(size_t)cb * H_ + jb8 + j2] = make_float2(hv2[0], hv2[1]);
                asm volatile("s_waitcnt vmcnt(0)" ::: "memory");
                if (l == 0) {
                    unsigned old = __hip_atomic_fetch_add(&ctr[1088 + (db >> 3) * 16], 1u, __ATOMIC_RELAXED, __HIP_MEMORY_SCOPE_AGENT);
                    if ((old & 15u) == 15u) {
                        unsigned r = __hip_atomic_fetch_add(&ctr[1344], 1u, __ATOMIC_RELAXED, __HIP_MEMORY_SCOPE_AGENT);
                        if ((r & 15u) == 15u) {
                            #pragma unroll
                            for (int i = 0; i < 16; ++i) stA32(&ctr[256 + i * 16], (unsigned)(t + 1));
                        }
                    }
                }
            }
        }
    }
}

extern "C" void kernel_launch(void* const* d_in, const int* in_sizes, int n_in,
                              void* d_out, int out_size, void* d_ws, size_t ws_size,
                              hipStream_t stream) {
    const float* x  = (const float*)d_in[0];
    const float* W0 = (const float*)d_in[1];
    const float* U0 = (const float*)d_in[2];
    const float* b0 = (const float*)d_in[3];
    const float* W1 = (const float*)d_in[4];
    const float* U1 = (const float*)d_in[5];
    const float* b1 = (const float*)d_in[6];
    float* out = (float*)d_out;

    char* ws = (char*)d_ws;
    const size_t off_h1 = 0;          // 32 MiB  h1 fp16 [T][B][H]
    const size_t off_h2 = 33554432;   // 32 MiB  h2 fp16 [T][B][H]
    const size_t off_xz = 67108864;   //  8 MiB  xz ring fp16 [4][8][B][4H]
    const size_t off_zp = 75497472;   // 64 KiB  fp16 zeros
    const size_t off_ct = 75563008;   //  8 KiB  counters

    _Float16* h1  = (_Float16*)(ws + off_h1);
    _Float16* h2  = (_Float16*)(ws + off_h2);
    _Float16* xzr = (_Float16*)(ws + off_xz);
    _Float16* zp  = (_Float16*)(ws + off_zp);
    unsigned* ctr = (unsigned*)(ws + off_ct);

    // reset zero page + counters every launch (graph-capture safe)
    hipMemsetAsync(ws + off_zp, 0, 65536 + 8192, stream);

    hipLaunchKernelGGL(lstm9, dim3(256), dim3(NT), 0, stream,
                       x, W0, U0, b0, W1, U1, b1,
                       h1, h2, xzr, zp, ctr, out);
}